// Round 2
// baseline (331.622 us; speedup 1.0000x reference)
//
#include <hip/hip_runtime.h>
#include <hip/hip_cooperative_groups.h>
#include <math.h>

namespace cg = cooperative_groups;

#define N    8192
#define BLK  256
#define NBX  32               // 32x32 block tiling for the rank phase
#define TBL  16384            // hash slots = 2x N, load factor <= 0.5

// f32 hash pipeline — byte-identical math to the verified version (absmax 0.0):
//   i = rint((log512 - log w)/log 1.2), di = 128/1.2^i, qx = rint(x/di - 0.5).
// Field bounds: qx,qy in [0,1035] (11 bits), i,j in [0,23] (5 bits).
// 5|5|11|11 bit-pack is lexicographic in (j,i,qy,qx) — same order/equality
// as the reference decimal code. Max code < 0xC0000000 (j<=23), so
// 0xFFFFFFFF is a safe empty/sentinel value.
__device__ __forceinline__ unsigned int hash_code32(float x, float y, float w, float h) {
    const float LOG_ALPHA = (float)log((double)1.2f);
    const float LOGW0     = (float)log(512.0);
    float i_f = rintf((LOGW0 - (float)log((double)w)) / LOG_ALPHA);
    float j_f = rintf((LOGW0 - (float)log((double)h)) / LOG_ALPHA);
    float pi  = (float)pow((double)1.2f, (double)i_f);
    float pj  = (float)pow((double)1.2f, (double)j_f);
    float qx  = rintf(x / (128.0f / pi) - 0.5f);
    float qy  = rintf(y / (128.0f / pj) - 0.5f);
    return (unsigned int)qx
         | ((unsigned int)qy  << 11)
         | ((unsigned int)i_f << 22)
         | ((unsigned int)j_f << 27);
}

__device__ __forceinline__ unsigned int hslot(unsigned int code) {
    return (code * 2654435761u) >> 18;   // top 14 bits -> [0, TBL)
}

// Single cooperative kernel, 1024 blocks x 256 threads (4 blocks/CU).
// P0: init hash table + rank + out (workspace is poisoned each iteration).
// P1: 32 blocks compute codes once, v64[i] = code<<32|conf_bits, and do
//     hash-insert + atomicMax key (key = conf_bits<<32 | N-1-i: group-max
//     conf, tie -> smaller index — exactly reference argmax order).
// P2: block (bx,by): stage winner-codes of j-slice 'by' into LDS via table
//     lookup (winner j <=> low32(slot key) == N-1-j); rank_i += #winners
//     in slice with code < code_i. Diagonal blocks record win[i].
// P3: winners scatter i at out[rank_i]; all-conf-zero group -> reference
//     argmax of an all-zero column is 0.
__global__ void __launch_bounds__(BLK, 4)
k_all(const float4* __restrict__ rects, const float* __restrict__ conf,
      unsigned long long* __restrict__ v64,
      unsigned int* __restrict__ tcode,
      unsigned long long* __restrict__ tkey,
      int* __restrict__ win, int* __restrict__ rank,
      int* __restrict__ out) {
    cg::grid_group grid = cg::this_grid();
    const int t  = threadIdx.x;
    const int b  = blockIdx.x;          // 0..1023
    const int bx = b & (NBX - 1);
    const int by = b >> 5;
    const int gt = b * BLK + t;         // 0..262143

    // ---- P0: init (262144 threads cover 49152 init words) ----
    if (gt < TBL)                 tcode[gt] = 0xFFFFFFFFu;
    else if (gt < 2 * TBL)        tkey[gt - TBL] = 0ULL;
    else if (gt < 2 * TBL + N)    rank[gt - 2 * TBL] = 0;
    else if (gt < 2 * TBL + 2 * N) out[gt - 2 * TBL - N] = 0;
    grid.sync();

    // ---- P1: codes + hash insert (blocks 0..31 only) ----
    if (b < NBX) {
        int i = b * BLK + t;
        float4 r = rects[i];
        unsigned int code = hash_code32(r.x, r.y, r.z, r.w);
        unsigned int cb   = __float_as_uint(conf[i]);
        v64[i] = ((unsigned long long)code << 32) | cb;
        unsigned int h = hslot(code);
        for (;;) {
            unsigned int prev = atomicCAS(&tcode[h], 0xFFFFFFFFu, code);
            if (prev == 0xFFFFFFFFu || prev == code) break;
            h = (h + 1) & (TBL - 1);
        }
        unsigned long long key = ((unsigned long long)cb << 32)
                               | (unsigned int)(N - 1 - i);
        atomicMax(&tkey[h], key);
    }
    grid.sync();

    // ---- P2: winner lookup + sliced rank ----
    __shared__ __align__(16) unsigned int s_wc[BLK];
    {
        int j = by * BLK + t;
        unsigned int cj = (unsigned int)(v64[j] >> 32);
        unsigned int h = hslot(cj);
        while (tcode[h] != cj) h = (h + 1) & (TBL - 1);
        int wj = ((unsigned int)tkey[h] == (unsigned int)(N - 1 - j));
        s_wc[t] = wj ? cj : 0xFFFFFFFFu;   // sentinel > any real code
        if (by == bx) win[j] = wj;         // j == i on diagonal blocks
    }
    int i = bx * BLK + t;
    unsigned int ci = (unsigned int)(v64[i] >> 32);
    __syncthreads();
    int r = 0;
    const uint4* s4 = (const uint4*)s_wc;
    #pragma unroll 8
    for (int k = 0; k < BLK / 4; ++k) {
        uint4 c = s4[k];
        r += (int)(c.x < ci) + (int)(c.y < ci)
           + (int)(c.z < ci) + (int)(c.w < ci);
    }
    if (r) atomicAdd(&rank[i], r);
    grid.sync();

    // ---- P3: scatter (blocks 0..31 only) ----
    if (b < NBX) {
        int ii = b * BLK + t;
        if (win[ii]) {
            unsigned int cb = (unsigned int)v64[ii];  // conf bits
            out[rank[ii]] = (cb == 0u) ? 0 : ii;
        }
    }
}

extern "C" void kernel_launch(void* const* d_in, const int* in_sizes, int n_in,
                              void* d_out, int out_size, void* d_ws, size_t ws_size,
                              hipStream_t stream) {
    const float4* rects = (const float4*)d_in[0];   // (8192, 4) f32
    const float*  conf  = (const float*)d_in[1];    // (8192,)  f32
    int* out = (int*)d_out;                         // int32 indices

    char* ws = (char*)d_ws;
    unsigned long long* v64  = (unsigned long long*)ws;              // 64 KiB
    unsigned int*       tcode = (unsigned int*)(ws + 65536);         // 64 KiB
    unsigned long long* tkey  = (unsigned long long*)(ws + 131072);  // 128 KiB
    int*                win   = (int*)(ws + 262144);                 // 32 KiB
    int*                rank  = (int*)(ws + 294912);                 // 32 KiB

    void* args[] = { (void*)&rects, (void*)&conf, (void*)&v64, (void*)&tcode,
                     (void*)&tkey, (void*)&win, (void*)&rank, (void*)&out };
    hipLaunchCooperativeKernel((const void*)k_all, dim3(NBX * NBX), dim3(BLK),
                               args, 0, stream);
}

// Round 3
// 286.822 us; speedup vs baseline: 1.1562x; 1.1562x over previous
//
#include <hip/hip_runtime.h>
#include <math.h>

#define N    8192
#define TBL  16384            // hash slots = 2x N, load factor <= 0.5
#define NB   1024             // D2 grid: 32 j-slices x 32 i-blocks

// f32 hash pipeline — byte-identical math to the R1-verified version
// (absmax 0.0). Field bounds: qx,qy in [0,1035] (11 bits), i,j in [0,23]
// (5 bits). 5|5|11|11 pack is lexicographic in (j,i,qy,qx) — same
// order/equality as the reference decimal code. Max code <= 0xBBFFFFFF,
// so 0xFFFFFFFF is a safe rank sentinel and code+1 never wraps.
__device__ __forceinline__ unsigned int hash_code32(float x, float y, float w, float h) {
    const float LOG_ALPHA = (float)log((double)1.2f);
    const float LOGW0     = (float)log(512.0);
    float i_f = rintf((LOGW0 - (float)log((double)w)) / LOG_ALPHA);
    float j_f = rintf((LOGW0 - (float)log((double)h)) / LOG_ALPHA);
    float pi  = (float)pow((double)1.2f, (double)i_f);
    float pj  = (float)pow((double)1.2f, (double)j_f);
    float qx  = rintf(x / (128.0f / pi) - 0.5f);
    float qy  = rintf(y / (128.0f / pj) - 0.5f);
    return (unsigned int)qx
         | ((unsigned int)qy  << 11)
         | ((unsigned int)i_f << 22)
         | ((unsigned int)j_f << 27);
}

__device__ __forceinline__ unsigned int hslot(unsigned int code) {
    return (code * 2654435761u) >> 18;   // top 14 bits -> [0, TBL)
}

// D1: codes + all zero-init (plain stores only). 32 blocks x 256.
__global__ void __launch_bounds__(256)
k_init(const float4* __restrict__ rects, const float* __restrict__ conf,
       unsigned long long* __restrict__ v64,
       unsigned int* __restrict__ tcode, unsigned long long* __restrict__ tkey,
       int* __restrict__ rank, int* __restrict__ out,
       unsigned int* __restrict__ cnt) {
    int i = blockIdx.x * 256 + threadIdx.x;
    float4 r = rects[i];
    unsigned int code = hash_code32(r.x, r.y, r.z, r.w);
    v64[i] = ((unsigned long long)code << 32)
           | (unsigned long long)__float_as_uint(conf[i]);
    out[i]  = 0;               // fill columns of reference argmax -> 0
    rank[i] = 0;
    tcode[2 * i]     = 0u;     // empty sentinel = 0 (codes stored as code+1)
    tcode[2 * i + 1] = 0u;
    tkey[2 * i]      = 0ULL;
    tkey[2 * i + 1]  = 0ULL;
    if (i == 0) { cnt[0] = 0u; cnt[1] = 0u; }
}

// D2: insert -> (capacity-safe spin) -> winner lookup + sliced rank ->
// last-block scatter. 1024 blocks x 256, 8 blocks/CU guaranteed
// (launch_bounds(256,8) => <=64 VGPR => capacity 2048 >= 1024: every block
// resident, so spinning on the insert counter cannot deadlock; inserter
// blocks never wait before bumping it).
__global__ void __launch_bounds__(256, 8)
k_main(const unsigned long long* __restrict__ v64,
       unsigned int* __restrict__ tcode, unsigned long long* __restrict__ tkey,
       int* __restrict__ win, int* __restrict__ rank,
       int* __restrict__ out, unsigned int* __restrict__ cnt) {
    const int t  = threadIdx.x;
    const int b  = blockIdx.x;
    const int bx = b & 31;          // i-block
    const int by = b >> 5;          // j-slice

    // ---- insert phase: blocks 0..31 cover all 8192 elements ----
    if (b < 32) {
        int i = b * 256 + t;
        unsigned long long v = v64[i];
        unsigned int code = (unsigned int)(v >> 32);
        unsigned int tag  = code + 1u;
        unsigned int h = hslot(code);
        for (;;) {
            unsigned int prev = atomicCAS(&tcode[h], 0u, tag);
            if (prev == 0u || prev == tag) break;
            h = (h + 1) & (TBL - 1);
        }
        // key: max conf, tie -> smaller index (reference argmax order)
        atomicMax(&tkey[h], (v << 32) | (unsigned int)(N - 1 - i));
        __threadfence();            // drain my atomics before signaling
        __syncthreads();
        if (t == 0)
            __hip_atomic_fetch_add(&cnt[0], 1u, __ATOMIC_RELEASE,
                                   __HIP_MEMORY_SCOPE_AGENT);
    }

    // ---- wait until all 32 inserter blocks are done ----
    if (t == 0) {
        while (__hip_atomic_load(&cnt[0], __ATOMIC_ACQUIRE,
                                 __HIP_MEMORY_SCOPE_AGENT) < 32u)
            __builtin_amdgcn_s_sleep(2);
    }
    __syncthreads();

    // ---- winner lookup for j-slice 'by' + rank scan for i-block 'bx' ----
    __shared__ __align__(16) unsigned int s_wc[256];
    {
        int j = by * 256 + t;
        unsigned int cj  = (unsigned int)(v64[j] >> 32);
        unsigned int tag = cj + 1u;
        unsigned int h = hslot(cj);
        while (tcode[h] != tag) h = (h + 1) & (TBL - 1);
        int wj = ((unsigned int)tkey[h] == (unsigned int)(N - 1 - j));
        s_wc[t] = wj ? cj : 0xFFFFFFFFu;   // sentinel > any real code
        if (bx == by) win[j] = wj;         // diagonal blocks record winners
    }
    int i = bx * 256 + t;
    unsigned int ci = (unsigned int)(v64[i] >> 32);
    __syncthreads();
    int r = 0;
    const uint4* s4 = (const uint4*)s_wc;
    #pragma unroll 8
    for (int k = 0; k < 64; ++k) {
        uint4 c = s4[k];
        r += (int)(c.x < ci) + (int)(c.y < ci)
           + (int)(c.z < ci) + (int)(c.w < ci);
    }
    if (r) atomicAdd(&rank[i], r);

    // ---- last-block scatter (rocPRIM-style ticket) ----
    __threadfence();                // publish win[] stores + rank adds
    __syncthreads();
    __shared__ int s_last;
    if (t == 0) {
        unsigned int tk = __hip_atomic_fetch_add(&cnt[1], 1u, __ATOMIC_ACQ_REL,
                                                 __HIP_MEMORY_SCOPE_AGENT);
        s_last = (tk == NB - 1);
    }
    __syncthreads();
    if (s_last) {
        __threadfence();            // acquire: invalidate before plain reads
        for (int k = t; k < N; k += 256) {
            if (win[k]) {
                unsigned int cb = (unsigned int)v64[k];  // conf bits
                out[rank[k]] = (cb == 0u) ? 0 : k;  // all-conf-0 group -> 0
            }
        }
    }
}

extern "C" void kernel_launch(void* const* d_in, const int* in_sizes, int n_in,
                              void* d_out, int out_size, void* d_ws, size_t ws_size,
                              hipStream_t stream) {
    const float4* rects = (const float4*)d_in[0];   // (8192, 4) f32
    const float*  conf  = (const float*)d_in[1];    // (8192,)  f32
    int* out = (int*)d_out;                         // int32 indices

    char* ws = (char*)d_ws;
    unsigned long long* v64   = (unsigned long long*)ws;             // 64 KiB
    unsigned int*       tcode = (unsigned int*)(ws + 65536);         // 64 KiB
    unsigned long long* tkey  = (unsigned long long*)(ws + 131072);  // 128 KiB
    int*                win   = (int*)(ws + 262144);                 // 32 KiB
    int*                rank  = (int*)(ws + 294912);                 // 32 KiB
    unsigned int*       cnt   = (unsigned int*)(ws + 327680);        // 8 B

    k_init<<<N / 256, 256, 0, stream>>>(rects, conf, v64, tcode, tkey,
                                        rank, out, cnt);
    k_main<<<NB, 256, 0, stream>>>(v64, tcode, tkey, win, rank, out, cnt);
}

// Round 4
// 147.788 us; speedup vs baseline: 2.2439x; 1.9408x over previous
//
#include <hip/hip_runtime.h>
#include <math.h>

#define N    8192
#define TBL  16384            // hash slots = 2x N, load factor <= 0.5
#define NB   1024             // K3 grid: 32 j-slices x 32 i-blocks

// f32 hash pipeline — byte-identical math to the verified version (absmax
// 0.0 in R1/R3). Field bounds: qx,qy in [0,1035] (11 bits), i,j in [0,23]
// (5 bits). 5|5|11|11 pack is lexicographic in (j,i,qy,qx) — same
// order/equality as the reference decimal code. Max code <= 0xBBFFFFFF,
// so 0xFFFFFFFF is a safe rank sentinel and code+1 never wraps.
__device__ __forceinline__ unsigned int hash_code32(float x, float y, float w, float h) {
    const float LOG_ALPHA = (float)log((double)1.2f);
    const float LOGW0     = (float)log(512.0);
    float i_f = rintf((LOGW0 - (float)log((double)w)) / LOG_ALPHA);
    float j_f = rintf((LOGW0 - (float)log((double)h)) / LOG_ALPHA);
    float pi  = (float)pow((double)1.2f, (double)i_f);
    float pj  = (float)pow((double)1.2f, (double)j_f);
    float qx  = rintf(x / (128.0f / pi) - 0.5f);
    float qy  = rintf(y / (128.0f / pj) - 0.5f);
    return (unsigned int)qx
         | ((unsigned int)qy  << 11)
         | ((unsigned int)i_f << 22)
         | ((unsigned int)j_f << 27);
}

__device__ __forceinline__ unsigned int hslot(unsigned int code) {
    return (code * 2654435761u) >> 18;   // top 14 bits -> [0, TBL)
}

// K1: zero table/rank/out/tickets + compute codes. Plain stores only,
// no cross-block deps. 64 blocks x 256 = 16384 threads.
__global__ void __launch_bounds__(256)
k_init(const float4* __restrict__ rects, const float* __restrict__ conf,
       unsigned long long* __restrict__ v64,
       unsigned int* __restrict__ tcode, unsigned long long* __restrict__ tkey,
       int* __restrict__ rank, int* __restrict__ out,
       unsigned int* __restrict__ tick) {
    int gt = blockIdx.x * 256 + threadIdx.x;    // 0..16383
    tcode[gt] = 0u;            // empty sentinel = 0 (codes stored as code+1)
    tkey[gt]  = 0ULL;
    if (gt < N) {
        float4 r = rects[gt];
        unsigned int code = hash_code32(r.x, r.y, r.z, r.w);
        v64[gt] = ((unsigned long long)code << 32)
                | (unsigned long long)__float_as_uint(conf[gt]);
        rank[gt] = 0;
        out[gt]  = 0;          // fill columns of reference argmax -> 0
    }
    if (gt < 32) tick[gt * 32] = 0u;   // 32 ticket counters, 128 B apart
}

// K2: hash insert. 32 blocks x 256. Claim slot by CAS, then group-argmax
// via 64-bit atomicMax of (conf_bits<<32 | N-1-i): max conf, tie ->
// smaller index — exactly the reference argmax order.
__global__ void __launch_bounds__(256)
k_insert(const unsigned long long* __restrict__ v64,
         unsigned int* __restrict__ tcode,
         unsigned long long* __restrict__ tkey) {
    int i = blockIdx.x * 256 + threadIdx.x;
    unsigned long long v = v64[i];
    unsigned int code = (unsigned int)(v >> 32);
    unsigned int tag  = code + 1u;
    unsigned int h = hslot(code);
    for (;;) {
        unsigned int prev = atomicCAS(&tcode[h], 0u, tag);
        if (prev == 0u || prev == tag) break;
        h = (h + 1) & (TBL - 1);
    }
    atomicMax(&tkey[h], (v << 32) | (unsigned int)(N - 1 - i));
}

// K3: fused winner-lookup + sliced rank + last-arriver scatter. No spins.
// Block (bx,by): stage winner-codes of j-slice 'by' (winner j <=>
// low32(slot key) == N-1-j; losers get sentinel 0xFFFFFFFF > any code),
// add partial rank for i-block 'bx' (rank_i = #distinct codes < code_i ==
// #winner codes < code_i, since every distinct code has exactly one
// winner). The 32nd block to finish an i-block takes the ticket,
// recomputes winner flags for those 256 i's, and scatters.
__global__ void __launch_bounds__(256)
k_rank(const unsigned long long* __restrict__ v64,
       const unsigned int* __restrict__ tcode,
       const unsigned long long* __restrict__ tkey,
       int* __restrict__ rank, int* __restrict__ out,
       unsigned int* __restrict__ tick) {
    const int t  = threadIdx.x;
    const int b  = blockIdx.x;
    const int bx = b & 31;          // i-block
    const int by = b >> 5;          // j-slice

    __shared__ __align__(16) unsigned int s_wc[256];
    {
        int j = by * 256 + t;
        unsigned int cj  = (unsigned int)(v64[j] >> 32);
        unsigned int tag = cj + 1u;
        unsigned int h = hslot(cj);
        while (tcode[h] != tag) h = (h + 1) & (TBL - 1);
        int wj = ((unsigned int)tkey[h] == (unsigned int)(N - 1 - j));
        s_wc[t] = wj ? cj : 0xFFFFFFFFu;
    }
    int i = bx * 256 + t;
    unsigned int ci = (unsigned int)(v64[i] >> 32);
    __syncthreads();
    int r = 0;
    const uint4* s4 = (const uint4*)s_wc;
    #pragma unroll 8
    for (int k = 0; k < 64; ++k) {
        uint4 c = s4[k];
        r += (int)(c.x < ci) + (int)(c.y < ci)
           + (int)(c.z < ci) + (int)(c.w < ci);
    }
    if (r) atomicAdd(&rank[i], r);

    // ---- per-i-block ticket: last of the 32 contributors scatters ----
    __threadfence();                // publish this block's rank adds
    __syncthreads();                // all 256 threads' adds are fenced
    __shared__ int s_last;
    if (t == 0) {
        unsigned int tk = __hip_atomic_fetch_add(&tick[bx * 32], 1u,
                                                 __ATOMIC_ACQ_REL,
                                                 __HIP_MEMORY_SCOPE_AGENT);
        s_last = (tk == 31u);
    }
    __syncthreads();
    if (s_last) {
        __threadfence();            // acquire side: see others' rank adds
        unsigned long long vi = v64[i];
        unsigned int ci2 = (unsigned int)(vi >> 32);
        unsigned int tag = ci2 + 1u;
        unsigned int h = hslot(ci2);
        while (tcode[h] != tag) h = (h + 1) & (TBL - 1);
        if ((unsigned int)tkey[h] == (unsigned int)(N - 1 - i)) {
            // conf==0 winner => whole group conf 0 => all-zero score
            // column => reference argmax returns 0.
            out[rank[i]] = ((unsigned int)vi == 0u) ? 0 : i;
        }
    }
}

extern "C" void kernel_launch(void* const* d_in, const int* in_sizes, int n_in,
                              void* d_out, int out_size, void* d_ws, size_t ws_size,
                              hipStream_t stream) {
    const float4* rects = (const float4*)d_in[0];   // (8192, 4) f32
    const float*  conf  = (const float*)d_in[1];    // (8192,)  f32
    int* out = (int*)d_out;                         // int32 indices

    char* ws = (char*)d_ws;
    unsigned long long* v64   = (unsigned long long*)ws;             // 64 KiB
    unsigned int*       tcode = (unsigned int*)(ws + 65536);         // 64 KiB
    unsigned long long* tkey  = (unsigned long long*)(ws + 131072);  // 128 KiB
    int*                rank  = (int*)(ws + 262144);                 // 32 KiB
    unsigned int*       tick  = (unsigned int*)(ws + 294912);        // 4 KiB

    k_init  <<<TBL / 256, 256, 0, stream>>>(rects, conf, v64, tcode, tkey,
                                            rank, out, tick);
    k_insert<<<N / 256, 256, 0, stream>>>(v64, tcode, tkey);
    k_rank  <<<NB, 256, 0, stream>>>(v64, tcode, tkey, rank, out, tick);
}